// Round 3
// baseline (342.353 us; speedup 1.0000x reference)
//
#include <hip/hip_runtime.h>
#include <hip/hip_fp16.h>

// EdgeVar: mean over graphs of mean over edges of (||pos[dst]-pos[src]|| - 1)^2.
// R3: dual-axis bucketing. R2 post-mortem showed the monolithic kernel is bound
// by L2 random-request rate (25.6M gather lines @ ~0.28 lines/cyc/CU). This
// version converts all random access into streams + LDS.

typedef int iv4 __attribute__((ext_vector_type(4)));

#define GBINS 1024
#define BUK   32            // buckets per axis
#define NBUK  1024          // BUK*BUK bucket pairs
#define CHUNK 8192          // edges per phase-A block
#define MAXD  6656          // max nodes per bucket (LDS limit); N <= 32*6656

__device__ __forceinline__ uint32_t divm(uint32_t x, unsigned long long magic) {
    return (uint32_t)((x * magic) >> 40);   // exact floor(x/d) for x < 2^22
}

__global__ void pack_nodes16(const float2* __restrict__ pos, const int* __restrict__ batch,
                             uint32_t* __restrict__ pos16, unsigned short* __restrict__ gid16,
                             int N) {
    int i = blockIdx.x * blockDim.x + threadIdx.x;
    if (i < N) {
        float2 p = pos[i];
        __half2 h; h.x = __float2half_rn(p.x); h.y = __float2half_rn(p.y);
        uint32_t u; __builtin_memcpy(&u, &h, 4);
        pos16[i] = u;
        gid16[i] = (unsigned short)batch[i];
    }
}

// ---------------- Phase A: counting-sort edges into 1024 (src,dst) buckets ----
__global__ __launch_bounds__(1024)
void phaseA(const int* __restrict__ srcL, const int* __restrict__ dstL,
            uint32_t* __restrict__ lists, uint32_t* __restrict__ cursors,
            int E, uint32_t dnode, unsigned long long magic, uint32_t cap) {
    __shared__ uint32_t cnt[NBUK];         // per-bucket count (tid == bucket id)
    __shared__ uint32_t lofs[NBUK + 1];    // exclusive offsets into stage
    __shared__ uint32_t gbase[NBUK];       // global base per bucket
    __shared__ uint32_t stage[CHUNK];      // 32KB reorder buffer
    const int tid = threadIdx.x;
    cnt[tid] = 0;
    __syncthreads();

    const int base = blockIdx.x * CHUNK;
    const bool amok = ((E & 3) == 0);      // iv4 alignment of dstL needs E%4==0
    int bid[8]; uint32_t rank[8], rec[8];

    #pragma unroll
    for (int h = 0; h < 2; ++h) {
        const int e0 = base + h * 4096 + 4 * tid;
        iv4 sv, dv;
        const bool vec = amok && (e0 + 3 < E);
        if (vec) {
            sv = __builtin_nontemporal_load((const iv4*)(srcL + e0));
            dv = __builtin_nontemporal_load((const iv4*)(dstL + e0));
        }
        #pragma unroll
        for (int k = 0; k < 4; ++k) {
            const int j = h * 4 + k;
            const int e = e0 + k;
            int s, d;
            if (vec)          { s = sv[k];   d = dv[k]; }
            else if (e < E)   { s = srcL[e]; d = dstL[e]; }
            else              { bid[j] = -1; continue; }
            uint32_t bs = divm((uint32_t)s, magic), bd = divm((uint32_t)d, magic);
            uint32_t sl = (uint32_t)s - bs * dnode;
            uint32_t dl = (uint32_t)d - bd * dnode;
            bid[j]  = (int)(bs * BUK + bd);
            rec[j]  = (sl << 13) | dl;                 // sl,dl < 6656 < 2^13
            rank[j] = atomicAdd(&cnt[bid[j]], 1u);
        }
    }
    __syncthreads();

    // in-place inclusive scan of cnt[1024] (tid == element)
    const uint32_t mycnt = cnt[tid];
    for (int off = 1; off < NBUK; off <<= 1) {
        uint32_t x = (tid >= off) ? cnt[tid - off] : 0u;
        __syncthreads();
        cnt[tid] += x;
        __syncthreads();
    }
    lofs[tid] = cnt[tid] - mycnt;
    if (tid == NBUK - 1) lofs[NBUK] = cnt[tid];
    gbase[tid] = atomicAdd(&cursors[tid], mycnt);
    __syncthreads();

    // scatter into LDS stage, bucket-grouped
    #pragma unroll
    for (int j = 0; j < 8; ++j)
        if (bid[j] >= 0) stage[lofs[bid[j]] + rank[j]] = rec[j];
    __syncthreads();

    // coalesced segment copy to global bucket regions
    const int n = (int)lofs[NBUK];
    for (int i = tid; i < n; i += 1024) {
        int b = 0;
        #pragma unroll
        for (int st = 512; st; st >>= 1)
            if (lofs[b + st] <= (uint32_t)i) b += st;
        const uint32_t gpos = gbase[b] + ((uint32_t)i - lofs[b]);
        if (gpos < cap) lists[(size_t)b * cap + gpos] = stage[i];
    }
}

// ---------------- Phase B: one block per bucket pair, slices in LDS ----------
__global__ __launch_bounds__(1024)
void phaseB(const uint32_t* __restrict__ pos16, const unsigned short* __restrict__ gid16,
            const uint32_t* __restrict__ lists, const uint32_t* __restrict__ cursors,
            float* __restrict__ gsum, float* __restrict__ gcnt,
            int N, uint32_t dnode, uint32_t cap) {
    __shared__ uint32_t spos[MAXD];   // 26.6KB  src slice packed half2
    __shared__ uint32_t dposA[MAXD];  // 26.6KB  dst slice packed half2
    __shared__ float hs[GBINS];       // 4KB
    __shared__ float hc[GBINS];       // 4KB     total ~61.3KB -> 2 blocks/CU
    const int tid = threadIdx.x;
    const int bs = blockIdx.x >> 5, bd = blockIdx.x & (BUK - 1);
    const int s0 = bs * (int)dnode, d0 = bd * (int)dnode;
    const int ns = min((int)dnode, N - s0);
    const int nd = min((int)dnode, N - d0);
    for (int i = tid; i < ns; i += 1024) spos[i]  = pos16[s0 + i];
    for (int i = tid; i < nd; i += 1024) dposA[i] = pos16[d0 + i];
    for (int i = tid; i < GBINS; i += 1024) { hs[i] = 0.f; hc[i] = 0.f; }
    __syncthreads();

    const uint32_t cnt = min(cursors[blockIdx.x], cap);
    const uint32_t* __restrict__ lp = lists + (size_t)blockIdx.x * cap;
    const unsigned short* __restrict__ sg = gid16 + s0;   // 13.3KB window: L1-hot
    for (uint32_t i = tid; i < cnt; i += 1024) {
        const uint32_t r = lp[i];
        const uint32_t sl = r >> 13, dl = r & 8191u;
        const uint32_t ua = spos[sl], ub = dposA[dl];
        const int g = sg[sl];
        __half2 ha, hb;
        __builtin_memcpy(&ha, &ua, 4);
        __builtin_memcpy(&hb, &ub, 4);
        const float dx = __half2float(hb.x) - __half2float(ha.x);
        const float dy = __half2float(hb.y) - __half2float(ha.y);
        const float t  = sqrtf(fmaf(dx, dx, dy * dy)) - 1.f;
        atomicAdd(&hs[g], t * t);
        atomicAdd(&hc[g], 1.f);
    }
    __syncthreads();
    for (int g = tid; g < GBINS; g += 1024) {
        const float c = hc[g];
        if (c != 0.f) { atomicAdd(&gsum[g], hs[g]); atomicAdd(&gcnt[g], c); }
    }
}

// ---------------- Fallback: R2 monolithic (request-bound but proven) ---------
__global__ __launch_bounds__(1024)
void edge_accum_mono(const float2* __restrict__ pos, const int* __restrict__ batch,
                     const int* __restrict__ src, const int* __restrict__ dst,
                     float* __restrict__ gsum, float* __restrict__ gcnt, int E) {
    __shared__ float ls[GBINS];
    __shared__ float lc[GBINS];
    for (int i = threadIdx.x; i < GBINS; i += blockDim.x) { ls[i] = 0.f; lc[i] = 0.f; }
    __syncthreads();
    const int tid = blockIdx.x * blockDim.x + threadIdx.x;
    const int stride = gridDim.x * blockDim.x;
    for (int i = tid; i < E; i += stride) {
        const int s = src[i], d = dst[i];
        const float2 a = pos[s], b = pos[d];
        const int g = batch[s];
        const float dx = b.x - a.x, dy = b.y - a.y;
        const float t = sqrtf(fmaf(dx, dx, dy * dy)) - 1.f;
        atomicAdd(&ls[g], t * t);
        atomicAdd(&lc[g], 1.f);
    }
    __syncthreads();
    for (int g = threadIdx.x; g < GBINS; g += blockDim.x) {
        const float c = lc[g];
        if (c != 0.f) { atomicAdd(&gsum[g], ls[g]); atomicAdd(&gcnt[g], c); }
    }
}

__global__ void finalize_kernel(const float* __restrict__ gsum,
                                const float* __restrict__ gcnt,
                                float* __restrict__ out,
                                const int* __restrict__ nG_ptr) {
    const int G = *nG_ptr;
    float v = 0.f;
    for (int g = threadIdx.x; g < G; g += blockDim.x)
        v += gsum[g] / fmaxf(gcnt[g], 1.f);
    __shared__ float w[16];
    for (int off = 32; off; off >>= 1) v += __shfl_down(v, off, 64);
    if ((threadIdx.x & 63) == 0) w[threadIdx.x >> 6] = v;
    __syncthreads();
    if (threadIdx.x == 0) {
        float s = 0.f;
        const int nw = (blockDim.x + 63) >> 6;
        for (int i = 0; i < nw; ++i) s += w[i];
        out[0] = s / (float)G;
    }
}

extern "C" void kernel_launch(void* const* d_in, const int* in_sizes, int n_in,
                              void* d_out, int out_size, void* d_ws, size_t ws_size,
                              hipStream_t stream) {
    const float2* pos   = (const float2*)d_in[0];
    const int*    ei    = (const int*)d_in[1];
    const int*    batch = (const int*)d_in[2];
    const int*    nG    = (const int*)d_in[3];

    const int N = in_sizes[0] / 2;
    const int E = in_sizes[1] / 2;
    const int* src = ei;
    const int* dst = ei + E;

    // ws layout: [gsum 4KB][gcnt 4KB][cursors 4KB][pad to 16KB][pos16 4N][gid16 2N][lists]
    float*    gsum    = (float*)d_ws;
    float*    gcnt    = gsum + GBINS;
    uint32_t* cursors = (uint32_t*)(gcnt + GBINS);
    const size_t pos16_off = 16384;
    const size_t gid16_off = pos16_off + (size_t)N * 4;
    const size_t lists_off = (gid16_off + (size_t)N * 2 + 255) & ~(size_t)255;
    const uint32_t dnode = (uint32_t)((N + BUK - 1) / BUK);
    const uint32_t cap   = (uint32_t)(E / NBUK + 2048);
    const size_t need = lists_off + (size_t)NBUK * cap * 4;
    const bool bucketed = (dnode <= MAXD) && (ws_size >= need) && (N < (1 << 22));

    (void)hipMemsetAsync(d_ws, 0, 12288, stream);   // gsum+gcnt+cursors

    if (bucketed) {
        uint32_t*       pos16 = (uint32_t*)((char*)d_ws + pos16_off);
        unsigned short* gid16 = (unsigned short*)((char*)d_ws + gid16_off);
        uint32_t*       lists = (uint32_t*)((char*)d_ws + lists_off);
        const unsigned long long magic = ((1ULL << 40) + dnode - 1) / dnode;

        pack_nodes16<<<(N + 255) / 256, 256, 0, stream>>>(pos, batch, pos16, gid16, N);
        phaseA<<<(E + CHUNK - 1) / CHUNK, 1024, 0, stream>>>(
            src, dst, lists, cursors, E, dnode, magic, cap);
        phaseB<<<NBUK, 1024, 0, stream>>>(
            pos16, gid16, lists, cursors, gsum, gcnt, N, dnode, cap);
    } else {
        edge_accum_mono<<<512, 1024, 0, stream>>>(pos, batch, src, dst, gsum, gcnt, E);
    }
    finalize_kernel<<<1, 1024, 0, stream>>>(gsum, gcnt, (float*)d_out, nG);
}

// Round 4
// 284.909 us; speedup vs baseline: 1.2016x; 1.2016x over previous
//
#include <hip/hip_runtime.h>
#include <hip/hip_fp16.h>

// EdgeVar R4: split + discriminate.
//   prep:  pack pos -> half2 table (800KB, L2-resident) and build graph
//          boundary table start[1025] from the SORTED batch_ids.
//   K1:    counts per graph.  Pure stream + LDS search + 1 LDS atomic/edge.
//   K2:    sums per graph.    Stream + 2 random pos16 gathers + 1 LDS atomic/edge.
//   finalize: mean(gsum / max(gcnt,1)).
// No batch[] gather anywhere (graph id via boundary search in LDS).

typedef int iv4 __attribute__((ext_vector_type(4)));

#define GBINS 1024

// ---- graph-of-node via guess + correction on sorted boundaries (LDS) -------
__device__ __forceinline__ int find_graph(int v, const int* __restrict__ ss, float scale) {
    int g = (int)((float)v * scale);       // ~floor(v*G/N); off by <=~3
    g = min(g, GBINS - 1);
    while (v < ss[g]) --g;                 // ss[0] = 0 guards the bottom
    while (v >= ss[g + 1]) ++g;            // ss[GBINS] = N guards the top
    return g;
}

__global__ void prep(const float2* __restrict__ pos, const int* __restrict__ batch,
                     uint32_t* __restrict__ pos16, int* __restrict__ startg, int N) {
    int i = blockIdx.x * blockDim.x + threadIdx.x;
    if (i >= N) return;
    float2 p = pos[i];
    __half2 h; h.x = __float2half_rn(p.x); h.y = __float2half_rn(p.y);
    uint32_t u; __builtin_memcpy(&u, &h, 4);
    pos16[i] = u;
    int b = batch[i];
    if (i == 0) { for (int g = 0; g <= b; ++g) startg[g] = 0; }
    else { int a = batch[i - 1]; for (int g = a + 1; g <= b; ++g) startg[g] = i; }
    if (i == N - 1) { for (int g = b + 1; g <= GBINS; ++g) startg[g] = N; }
}

// ---- K1: per-graph edge counts (src stream only) ---------------------------
__global__ __launch_bounds__(512)
void count_kernel(const int* __restrict__ src, const int* __restrict__ startg,
                  uint32_t* __restrict__ gcnt, int E, float scale) {
    __shared__ int ss[GBINS + 1];
    __shared__ uint32_t hc[GBINS];
    const int tid = threadIdx.x;
    for (int i = tid; i < GBINS + 1; i += 512) ss[i] = startg[i];
    for (int i = tid; i < GBINS; i += 512) hc[i] = 0u;
    __syncthreads();

    const int ngroups = E >> 2;
    const iv4* __restrict__ s4 = (const iv4*)src;
    const int gtid = blockIdx.x * 512 + tid, gstride = gridDim.x * 512;
    for (int i = gtid; i < ngroups; i += gstride) {
        iv4 sv = __builtin_nontemporal_load(&s4[i]);
        #pragma unroll
        for (int k = 0; k < 4; ++k)
            atomicAdd(&hc[find_graph(sv[k], ss, scale)], 1u);
    }
    for (int e = (ngroups << 2) + gtid; e < E; e += gstride)
        atomicAdd(&hc[find_graph(src[e], ss, scale)], 1u);

    __syncthreads();
    // striped flush: rotate bin order per block so same-address bursts spread
    for (int j = tid; j < GBINS; j += 512) {
        int g = (j + (blockIdx.x << 3)) & (GBINS - 1);
        uint32_t c = hc[g];
        if (c) atomicAdd(&gcnt[g], c);
    }
}

// ---- K2: per-graph sums of (||pd-ps||-1)^2 ---------------------------------
__global__ __launch_bounds__(512)
void sum_kernel(const int* __restrict__ src, const int* __restrict__ dst,
                const uint32_t* __restrict__ pos16, const int* __restrict__ startg,
                float* __restrict__ gsum, int E, float scale) {
    __shared__ int ss[GBINS + 1];
    __shared__ float hs[GBINS];
    const int tid = threadIdx.x;
    for (int i = tid; i < GBINS + 1; i += 512) ss[i] = startg[i];
    for (int i = tid; i < GBINS; i += 512) hs[i] = 0.f;
    __syncthreads();

    const int ngroups = E >> 2;
    const iv4* __restrict__ s4 = (const iv4*)src;
    const iv4* __restrict__ d4 = (const iv4*)dst;
    const int gtid = blockIdx.x * 512 + tid, gstride = gridDim.x * 512;
    for (int i = gtid; i < ngroups; i += gstride) {
        iv4 sv = __builtin_nontemporal_load(&s4[i]);
        iv4 dv = __builtin_nontemporal_load(&d4[i]);
        uint32_t ua[4], ub[4];
        #pragma unroll
        for (int k = 0; k < 4; ++k) { ua[k] = pos16[sv[k]]; ub[k] = pos16[dv[k]]; }
        #pragma unroll
        for (int k = 0; k < 4; ++k) {
            __half2 ha, hb;
            __builtin_memcpy(&ha, &ua[k], 4);
            __builtin_memcpy(&hb, &ub[k], 4);
            const float dx = __half2float(hb.x) - __half2float(ha.x);
            const float dy = __half2float(hb.y) - __half2float(ha.y);
            const float t  = sqrtf(fmaf(dx, dx, dy * dy)) - 1.f;
            atomicAdd(&hs[find_graph(sv[k], ss, scale)], t * t);
        }
    }
    for (int e = (ngroups << 2) + gtid; e < E; e += gstride) {
        const int s = src[e], d = dst[e];
        uint32_t ua = pos16[s], ub = pos16[d];
        __half2 ha, hb;
        __builtin_memcpy(&ha, &ua, 4);
        __builtin_memcpy(&hb, &ub, 4);
        const float dx = __half2float(hb.x) - __half2float(ha.x);
        const float dy = __half2float(hb.y) - __half2float(ha.y);
        const float t  = sqrtf(fmaf(dx, dx, dy * dy)) - 1.f;
        atomicAdd(&hs[find_graph(s, ss, scale)], t * t);
    }

    __syncthreads();
    for (int j = tid; j < GBINS; j += 512) {
        int g = (j + (blockIdx.x << 3)) & (GBINS - 1);
        float v = hs[g];
        if (v != 0.f) atomicAdd(&gsum[g], v);
    }
}

// ---- fallback (proven R2 path) if ws too small -----------------------------
__global__ __launch_bounds__(1024)
void edge_accum_mono(const float2* __restrict__ pos, const int* __restrict__ batch,
                     const int* __restrict__ src, const int* __restrict__ dst,
                     float* __restrict__ gsum, uint32_t* __restrict__ gcnt, int E) {
    __shared__ float ls[GBINS];
    __shared__ uint32_t lc[GBINS];
    for (int i = threadIdx.x; i < GBINS; i += blockDim.x) { ls[i] = 0.f; lc[i] = 0u; }
    __syncthreads();
    const int tid = blockIdx.x * blockDim.x + threadIdx.x;
    const int stride = gridDim.x * blockDim.x;
    for (int i = tid; i < E; i += stride) {
        const int s = src[i], d = dst[i];
        const float2 a = pos[s], b = pos[d];
        const int g = batch[s];
        const float dx = b.x - a.x, dy = b.y - a.y;
        const float t = sqrtf(fmaf(dx, dx, dy * dy)) - 1.f;
        atomicAdd(&ls[g], t * t);
        atomicAdd(&lc[g], 1u);
    }
    __syncthreads();
    for (int g = threadIdx.x; g < GBINS; g += blockDim.x) {
        const uint32_t c = lc[g];
        if (c) { atomicAdd(&gsum[g], ls[g]); atomicAdd(&gcnt[g], c); }
    }
}

__global__ void finalize_kernel(const float* __restrict__ gsum,
                                const uint32_t* __restrict__ gcnt,
                                float* __restrict__ out,
                                const int* __restrict__ nG_ptr) {
    const int G = *nG_ptr;
    float v = 0.f;
    for (int g = threadIdx.x; g < G; g += blockDim.x)
        v += gsum[g] / fmaxf((float)gcnt[g], 1.f);
    __shared__ float w[16];
    for (int off = 32; off; off >>= 1) v += __shfl_down(v, off, 64);
    if ((threadIdx.x & 63) == 0) w[threadIdx.x >> 6] = v;
    __syncthreads();
    if (threadIdx.x == 0) {
        float s = 0.f;
        const int nw = (blockDim.x + 63) >> 6;
        for (int i = 0; i < nw; ++i) s += w[i];
        out[0] = s / (float)G;
    }
}

extern "C" void kernel_launch(void* const* d_in, const int* in_sizes, int n_in,
                              void* d_out, int out_size, void* d_ws, size_t ws_size,
                              hipStream_t stream) {
    const float2* pos   = (const float2*)d_in[0];
    const int*    ei    = (const int*)d_in[1];
    const int*    batch = (const int*)d_in[2];
    const int*    nG    = (const int*)d_in[3];

    const int N = in_sizes[0] / 2;
    const int E = in_sizes[1] / 2;
    const int* src = ei;
    const int* dst = ei + E;

    // ws: [gsum f32 4KB][gcnt u32 4KB][start 1025*int @8KB][pos16 @16KB, 4N]
    float*    gsum   = (float*)d_ws;
    uint32_t* gcnt   = (uint32_t*)((char*)d_ws + 4096);
    int*      startg = (int*)((char*)d_ws + 8192);
    uint32_t* pos16  = (uint32_t*)((char*)d_ws + 16384);
    const size_t need = 16384 + (size_t)N * 4;
    const bool fast = (ws_size >= need) && (N >= 1);

    (void)hipMemsetAsync(d_ws, 0, 8192, stream);   // gsum + gcnt

    if (fast) {
        const float scale = (float)GBINS / (float)N;
        prep<<<(N + 255) / 256, 256, 0, stream>>>(pos, batch, pos16, startg, N);
        count_kernel<<<1024, 512, 0, stream>>>(src, startg, gcnt, E, scale);
        sum_kernel<<<1024, 512, 0, stream>>>(src, dst, pos16, startg, gsum, E, scale);
    } else {
        edge_accum_mono<<<512, 1024, 0, stream>>>(pos, batch, src, dst, gsum, gcnt, E);
    }
    finalize_kernel<<<1, 1024, 0, stream>>>(gsum, gcnt, (float*)d_out, nG);
}

// Round 5
// 257.179 us; speedup vs baseline: 1.3312x; 1.1078x over previous
//
#include <hip/hip_runtime.h>
#include <hip/hip_fp16.h>

// EdgeVar R5: single fused edge pass.
//   prep:  pos -> half2 table (800KB, L2-resident); startg[1025] boundaries
//          from the SORTED batch_ids (graph id via search, no batch gather).
//   fused: stream src+dst (NT int4 x2 = 8 edges/thread/iter), 16 divergent
//          pos16 gathers issued back-to-back (MSHR depth), LDS hist of
//          sums+counts, striped global flush.
//   finalize: mean(gsum / max(gcnt,1)).
// R4 analysis: divergent gathers are L1-MSHR-bound (~0.33-0.42 lines/cyc/CU);
// LDS atomics + boundary search are cheap. So: one pass, max gather ILP.

typedef int iv4 __attribute__((ext_vector_type(4)));

#define GBINS 1024

__device__ __forceinline__ int find_graph(int v, const int* __restrict__ ss, float scale) {
    int g = (int)((float)v * scale);       // ~floor(v*G/N); off by a few
    g = min(g, GBINS - 1);
    while (v < ss[g]) --g;                 // ss[0] = 0 guards the bottom
    while (v >= ss[g + 1]) ++g;            // ss[GBINS] = N guards the top
    return g;
}

__global__ void prep(const float2* __restrict__ pos, const int* __restrict__ batch,
                     uint32_t* __restrict__ pos16, int* __restrict__ startg, int N) {
    int i = blockIdx.x * blockDim.x + threadIdx.x;
    if (i >= N) return;
    float2 p = pos[i];
    __half2 h; h.x = __float2half_rn(p.x); h.y = __float2half_rn(p.y);
    uint32_t u; __builtin_memcpy(&u, &h, 4);
    pos16[i] = u;
    int b = batch[i];
    if (i == 0) { for (int g = 0; g <= b; ++g) startg[g] = 0; }
    else { int a = batch[i - 1]; for (int g = a + 1; g <= b; ++g) startg[g] = i; }
    if (i == N - 1) { for (int g = b + 1; g <= GBINS; ++g) startg[g] = N; }
}

__global__ __launch_bounds__(512)
void fused_kernel(const int* __restrict__ src, const int* __restrict__ dst,
                  const uint32_t* __restrict__ pos16, const int* __restrict__ startg,
                  float* __restrict__ gsum, uint32_t* __restrict__ gcnt,
                  int E, float scale) {
    __shared__ int ss[GBINS + 1];
    __shared__ float hs[GBINS];
    __shared__ uint32_t hc[GBINS];
    const int tid = threadIdx.x;
    for (int i = tid; i < GBINS + 1; i += 512) ss[i] = startg[i];
    for (int i = tid; i < GBINS; i += 512) { hs[i] = 0.f; hc[i] = 0u; }
    __syncthreads();

    const int g8 = ((E & 3) == 0) ? (E >> 3) : 0;   // dst 16B-aligned iff E%4==0
    const iv4* __restrict__ s4 = (const iv4*)src;
    const iv4* __restrict__ d4 = (const iv4*)dst;
    const int gtid = blockIdx.x * 512 + tid, gstride = gridDim.x * 512;

    for (int i = gtid; i < g8; i += gstride) {
        const iv4 sa = __builtin_nontemporal_load(&s4[2 * i]);
        const iv4 sb = __builtin_nontemporal_load(&s4[2 * i + 1]);
        const iv4 da = __builtin_nontemporal_load(&d4[2 * i]);
        const iv4 db = __builtin_nontemporal_load(&d4[2 * i + 1]);
        int sv[8], dv[8];
        #pragma unroll
        for (int k = 0; k < 4; ++k) { sv[k] = sa[k]; sv[4 + k] = sb[k];
                                      dv[k] = da[k]; dv[4 + k] = db[k]; }
        // issue all 16 divergent gathers back-to-back: fill the MSHR queue
        uint32_t ua[8], ub[8];
        #pragma unroll
        for (int k = 0; k < 8; ++k) { ua[k] = pos16[sv[k]]; ub[k] = pos16[dv[k]]; }
        #pragma unroll
        for (int k = 0; k < 8; ++k) {
            __half2 ha, hb;
            __builtin_memcpy(&ha, &ua[k], 4);
            __builtin_memcpy(&hb, &ub[k], 4);
            const float dx = __half2float(hb.x) - __half2float(ha.x);
            const float dy = __half2float(hb.y) - __half2float(ha.y);
            const float t  = sqrtf(fmaf(dx, dx, dy * dy)) - 1.f;
            const int g = find_graph(sv[k], ss, scale);
            atomicAdd(&hs[g], t * t);
            atomicAdd(&hc[g], 1u);
        }
    }
    for (int e = (g8 << 3) + gtid; e < E; e += gstride) {   // tail / unaligned
        const int s = src[e], d = dst[e];
        uint32_t ua = pos16[s], ub = pos16[d];
        __half2 ha, hb;
        __builtin_memcpy(&ha, &ua, 4);
        __builtin_memcpy(&hb, &ub, 4);
        const float dx = __half2float(hb.x) - __half2float(ha.x);
        const float dy = __half2float(hb.y) - __half2float(ha.y);
        const float t  = sqrtf(fmaf(dx, dx, dy * dy)) - 1.f;
        const int g = find_graph(s, ss, scale);
        atomicAdd(&hs[g], t * t);
        atomicAdd(&hc[g], 1u);
    }

    __syncthreads();
    // striped flush: rotate bin order per block to spread same-address bursts
    for (int j = tid; j < GBINS; j += 512) {
        const int g = (j + (blockIdx.x << 3)) & (GBINS - 1);
        const uint32_t c = hc[g];
        if (c) { atomicAdd(&gcnt[g], c); atomicAdd(&gsum[g], hs[g]); }
    }
}

// ---- fallback (proven R2 path) if ws too small -----------------------------
__global__ __launch_bounds__(1024)
void edge_accum_mono(const float2* __restrict__ pos, const int* __restrict__ batch,
                     const int* __restrict__ src, const int* __restrict__ dst,
                     float* __restrict__ gsum, uint32_t* __restrict__ gcnt, int E) {
    __shared__ float ls[GBINS];
    __shared__ uint32_t lc[GBINS];
    for (int i = threadIdx.x; i < GBINS; i += blockDim.x) { ls[i] = 0.f; lc[i] = 0u; }
    __syncthreads();
    const int tid = blockIdx.x * blockDim.x + threadIdx.x;
    const int stride = gridDim.x * blockDim.x;
    for (int i = tid; i < E; i += stride) {
        const int s = src[i], d = dst[i];
        const float2 a = pos[s], b = pos[d];
        const int g = batch[s];
        const float dx = b.x - a.x, dy = b.y - a.y;
        const float t = sqrtf(fmaf(dx, dx, dy * dy)) - 1.f;
        atomicAdd(&ls[g], t * t);
        atomicAdd(&lc[g], 1u);
    }
    __syncthreads();
    for (int g = threadIdx.x; g < GBINS; g += blockDim.x) {
        const uint32_t c = lc[g];
        if (c) { atomicAdd(&gsum[g], ls[g]); atomicAdd(&gcnt[g], c); }
    }
}

__global__ void finalize_kernel(const float* __restrict__ gsum,
                                const uint32_t* __restrict__ gcnt,
                                float* __restrict__ out,
                                const int* __restrict__ nG_ptr) {
    const int G = *nG_ptr;
    float v = 0.f;
    for (int g = threadIdx.x; g < G; g += blockDim.x)
        v += gsum[g] / fmaxf((float)gcnt[g], 1.f);
    __shared__ float w[16];
    for (int off = 32; off; off >>= 1) v += __shfl_down(v, off, 64);
    if ((threadIdx.x & 63) == 0) w[threadIdx.x >> 6] = v;
    __syncthreads();
    if (threadIdx.x == 0) {
        float s = 0.f;
        const int nw = (blockDim.x + 63) >> 6;
        for (int i = 0; i < nw; ++i) s += w[i];
        out[0] = s / (float)G;
    }
}

extern "C" void kernel_launch(void* const* d_in, const int* in_sizes, int n_in,
                              void* d_out, int out_size, void* d_ws, size_t ws_size,
                              hipStream_t stream) {
    const float2* pos   = (const float2*)d_in[0];
    const int*    ei    = (const int*)d_in[1];
    const int*    batch = (const int*)d_in[2];
    const int*    nG    = (const int*)d_in[3];

    const int N = in_sizes[0] / 2;
    const int E = in_sizes[1] / 2;
    const int* src = ei;
    const int* dst = ei + E;

    // ws: [gsum f32 4KB][gcnt u32 4KB][startg 1025*int @8KB][pos16 @16KB, 4N]
    float*    gsum   = (float*)d_ws;
    uint32_t* gcnt   = (uint32_t*)((char*)d_ws + 4096);
    int*      startg = (int*)((char*)d_ws + 8192);
    uint32_t* pos16  = (uint32_t*)((char*)d_ws + 16384);
    const size_t need = 16384 + (size_t)N * 4;
    const bool fast = (ws_size >= need) && (N >= 1);

    (void)hipMemsetAsync(d_ws, 0, 8192, stream);   // gsum + gcnt

    if (fast) {
        const float scale = (float)GBINS / (float)N;
        prep<<<(N + 255) / 256, 256, 0, stream>>>(pos, batch, pos16, startg, N);
        fused_kernel<<<1024, 512, 0, stream>>>(src, dst, pos16, startg, gsum, gcnt, E, scale);
    } else {
        edge_accum_mono<<<512, 1024, 0, stream>>>(pos, batch, src, dst, gsum, gcnt, E);
    }
    finalize_kernel<<<1, 1024, 0, stream>>>(gsum, gcnt, (float*)d_out, nG);
}